// Round 1
// baseline (334.028 us; speedup 1.0000x reference)
//
#include <hip/hip_runtime.h>
#include <hip/hip_bf16.h>
#include <cstdint>

using bf16 = __hip_bfloat16;
typedef __attribute__((ext_vector_type(8))) __bf16 bf16x8;
typedef __attribute__((ext_vector_type(4))) float f32x4;

#define MFMA16(a, b, c) __builtin_amdgcn_mfma_f32_16x16x32_bf16((a), (b), (c), 0, 0, 0)

// Async global->LDS 16B copy. LDS dest must be wave-uniform base + lane*16.
// Pointer AS casts via uintptr (CK idiom): low 32 bits of a generic LDS pointer
// are the LDS offset on gfx9+.
__device__ __forceinline__ void async16(void* lds_ptr, const void* gptr) {
  auto g = reinterpret_cast<__attribute__((address_space(1))) unsigned int*>(
      reinterpret_cast<uintptr_t>(gptr));
  auto l = reinterpret_cast<__attribute__((address_space(3))) unsigned int*>(
      static_cast<unsigned int>(reinterpret_cast<uintptr_t>(lds_ptr)));
  __builtin_amdgcn_global_load_lds(g, l, 16, 0, 0);
}

// ---------------------------------------------------------------- RMSNorm ----
// one block per row of x [4096][2048]; writes xn bf16.
__global__ __launch_bounds__(256) void rmsnorm_cast_k(
    const float* __restrict__ x, const float* __restrict__ sc, bf16* __restrict__ xn) {
  const int row = blockIdx.x, tid = threadIdx.x;
  const float4* xr = (const float4*)(x + (size_t)row * 2048);
  float4 a = xr[tid * 2], b = xr[tid * 2 + 1];
  float ss = a.x * a.x + a.y * a.y + a.z * a.z + a.w * a.w +
             b.x * b.x + b.y * b.y + b.z * b.z + b.w * b.w;
#pragma unroll
  for (int d = 1; d < 64; d <<= 1) ss += __shfl_xor(ss, d);
  __shared__ float sm[4];
  if ((tid & 63) == 0) sm[tid >> 6] = ss;
  __syncthreads();
  const float rinv = rsqrtf((sm[0] + sm[1] + sm[2] + sm[3]) * (1.0f / 2048.0f) + 1e-6f);
  const float4* sp = (const float4*)sc;
  float4 s0 = sp[tid * 2], s1 = sp[tid * 2 + 1];
  union { bf16 h[8]; bf16x8 v; } o;
  o.h[0] = __float2bfloat16(a.x * rinv * s0.x);
  o.h[1] = __float2bfloat16(a.y * rinv * s0.y);
  o.h[2] = __float2bfloat16(a.z * rinv * s0.z);
  o.h[3] = __float2bfloat16(a.w * rinv * s0.w);
  o.h[4] = __float2bfloat16(b.x * rinv * s1.x);
  o.h[5] = __float2bfloat16(b.y * rinv * s1.y);
  o.h[6] = __float2bfloat16(b.z * rinv * s1.z);
  o.h[7] = __float2bfloat16(b.w * rinv * s1.w);
  *(bf16x8*)(xn + (size_t)row * 2048 + tid * 8) = o.v;
}

// ------------------------------------------------- weight transpose + cast ----
// W f32 [2048][N] -> Wt bf16 [row_off + N][2048]  (Wt[n][k] = W[k][n])
__global__ void transpose_cast_k(const float* __restrict__ W, bf16* __restrict__ Wt,
                                 int N, int row_off) {
  __shared__ float t[32][33];
  const int n0 = blockIdx.x * 32, k0 = blockIdx.y * 32;
  const int tx = threadIdx.x, ty = threadIdx.y;
#pragma unroll
  for (int i = 0; i < 4; ++i)
    t[ty + 8 * i][tx] = W[(size_t)(k0 + ty + 8 * i) * N + n0 + tx];
  __syncthreads();
#pragma unroll
  for (int i = 0; i < 4; ++i)
    Wt[(size_t)(row_off + n0 + ty + 8 * i) * 2048 + k0 + tx] =
        __float2bfloat16(t[tx][ty + 8 * i]);
}

// V slice of QKV [4096][3072] (cols 2560..3071) -> Vt bf16 [16][128][1024]
__global__ void transpose_v_k(const bf16* __restrict__ qkv, bf16* __restrict__ vtb) {
  __shared__ bf16 t[32][33];
  const int bh = blockIdx.z, b = bh >> 2, g = bh & 3;
  const int s0 = blockIdx.x * 32, d0 = blockIdx.y * 32;
  const int tx = threadIdx.x, ty = threadIdx.y;
#pragma unroll
  for (int i = 0; i < 4; ++i)
    t[ty + 8 * i][tx] =
        qkv[(size_t)(b * 1024 + s0 + ty + 8 * i) * 3072 + 2560 + g * 128 + d0 + tx];
  __syncthreads();
#pragma unroll
  for (int i = 0; i < 4; ++i)
    vtb[((size_t)bh * 128 + d0 + ty + 8 * i) * 1024 + s0 + tx] = t[tx][ty + 8 * i];
}

__global__ void concat_bias_k(const float* __restrict__ bq, const float* __restrict__ bk,
                              const float* __restrict__ bv, float* __restrict__ o) {
  const int i = blockIdx.x * 256 + threadIdx.x;
  if (i < 2048) o[i] = bq[i];
  else if (i < 2560) o[i] = bk[i - 2048];
  else o[i] = bv[i - 2560];
}

// -------------------------------------------------------------------- GEMM ----
// C[M][N] = A[M][K] @ Bt[N][K]^T, bf16 in, f32 acc. 128x128 tile, BK=32, 4 waves.
// EPI 0: bf16 out, +bias (QKV). EPI 1: f32 out, +bias +res (Wo/W2).
// EPI 2: bf16 out, +bias, v*sigmoid(v)*v (W1).
template <int EPI>
__global__ __launch_bounds__(256, 2) void gemm_bt(
    const bf16* __restrict__ A, const bf16* __restrict__ Bt,
    const float* __restrict__ bias, const float* __restrict__ res,
    void* __restrict__ outp, int K, int ldout) {
  __shared__ __align__(16) unsigned char lds[16384];
  unsigned char* As = lds;
  unsigned char* Bs = lds + 8192;
  const int tid = threadIdx.x;
  const int lane = tid & 63, w = tid >> 6;
  const int wr = w >> 1, wc = w & 1;
  const int hi = lane >> 4, lo = lane & 15;
  const int brow = blockIdx.x * 128, bcol = blockIdx.y * 128;

  // staging: thread covers LDS bytes o0 and o0+4096 of each 8KB tile.
  // rows are 64B (=4 chunks of 16B); chunk swizzle c = s ^ ((r>>1)&3).
  const int o0 = tid * 16, o1 = o0 + 4096;
  const int r0 = o0 >> 6, c0 = ((o0 >> 4) & 3) ^ ((r0 >> 1) & 3);
  const int r1 = o1 >> 6, c1 = ((o1 >> 4) & 3) ^ ((r1 >> 1) & 3);
  const bf16* gA0 = A + (size_t)(brow + r0) * K + c0 * 8;
  const bf16* gA1 = A + (size_t)(brow + r1) * K + c1 * 8;
  const bf16* gB0 = Bt + (size_t)(bcol + r0) * K + c0 * 8;
  const bf16* gB1 = Bt + (size_t)(bcol + r1) * K + c1 * 8;

  const int rowA = wr * 64 + lo;
  const int rowB = wc * 64 + lo;
  const int swzA = (hi ^ ((rowA >> 1) & 3)) << 4;
  const int swzB = (hi ^ ((rowB >> 1) & 3)) << 4;

  f32x4 acc[4][4] = {};

  for (int k0 = 0; k0 < K; k0 += 32) {
    async16(As + o0, gA0 + k0);
    async16(As + o1, gA1 + k0);
    async16(Bs + o0, gB0 + k0);
    async16(Bs + o1, gB1 + k0);
    __syncthreads();
    bf16x8 af[4], bfr[4];
#pragma unroll
    for (int i = 0; i < 4; ++i)
      af[i] = *(const bf16x8*)(As + (rowA + i * 16) * 64 + swzA);
#pragma unroll
    for (int j = 0; j < 4; ++j)
      bfr[j] = *(const bf16x8*)(Bs + (rowB + j * 16) * 64 + swzB);
#pragma unroll
    for (int i = 0; i < 4; ++i)
#pragma unroll
      for (int j = 0; j < 4; ++j)
        acc[i][j] = MFMA16(af[i], bfr[j], acc[i][j]);
    __syncthreads();
  }

#pragma unroll
  for (int j = 0; j < 4; ++j) {
    const int col = bcol + wc * 64 + j * 16 + lo;
    const float bs = bias[col];
#pragma unroll
    for (int i = 0; i < 4; ++i) {
      const int row = brow + wr * 64 + i * 16 + hi * 4;
#pragma unroll
      for (int r = 0; r < 4; ++r) {
        float v = acc[i][j][r] + bs;
        if (EPI == 1) v += res[(size_t)(row + r) * ldout + col];
        if (EPI == 2) {
          const float sg = 1.0f / (1.0f + __expf(-v));
          v = v * sg * v;
        }
        if (EPI == 1)
          ((float*)outp)[(size_t)(row + r) * ldout + col] = v;
        else
          ((bf16*)outp)[(size_t)(row + r) * ldout + col] = __float2bfloat16(v);
      }
    }
  }
}

// --------------------------------------------------------------- attention ----
// grid (16 q-tiles, 64 b*h). Block 4 waves; wave w owns q rows [w*16, w*16+16).
// K tile [64 keys][128 d], Vt tile [128 d][64 keys], both LDS-swizzled.
__global__ __launch_bounds__(256, 2) void attn_fwd(
    const bf16* __restrict__ qkv, const bf16* __restrict__ vtb, bf16* __restrict__ out) {
  __shared__ __align__(16) unsigned char lds[40960];
  unsigned char* Ks = lds;
  unsigned char* Vs = lds + 16384;
  unsigned char* Ps = lds + 32768;
  const int tid = threadIdx.x, lane = tid & 63, w = tid >> 6;
  const int hi = lane >> 4, lo = lane & 15;
  const int qt = blockIdx.x, bh = blockIdx.y;
  const int b = bh >> 4, h = bh & 15, g = h >> 2;
  const size_t tok0 = (size_t)b * 1024;
  const int q0 = qt * 64;

  bf16x8 qf[4];
  {
    const bf16* qp = qkv + (tok0 + q0 + w * 16 + lo) * 3072 + h * 128 + hi * 8;
#pragma unroll
    for (int kc = 0; kc < 4; ++kc) qf[kc] = *(const bf16x8*)(qp + kc * 32);
  }

  float m[4] = {-1e30f, -1e30f, -1e30f, -1e30f};
  float l[4] = {0.f, 0.f, 0.f, 0.f};
  f32x4 oacc[8] = {};
  const float scale = 0.08838834764831845f;  // 1/sqrt(128)

  const int o = tid * 16;
  const bf16* kbase = qkv + tok0 * 3072 + 2048 + g * 128;
  const bf16* vbase = vtb + (size_t)(b * 4 + g) * 128 * 1024;

  for (int t = 0; t < 16; ++t) {
    const int kb = t * 64;
#pragma unroll
    for (int rd = 0; rd < 4; ++rd) {
      const int oo = o + rd * 4096;
      const int rK = oo >> 8, cK = ((oo >> 4) & 15) ^ (rK & 7);
      const int rV = oo >> 7, cV = ((oo >> 4) & 7) ^ (rV & 7);
      async16(Ks + oo, kbase + (size_t)(kb + rK) * 3072 + cK * 8);
      async16(Vs + oo, vbase + (size_t)rV * 1024 + kb + cV * 8);
    }
    __syncthreads();

    f32x4 sc[4] = {};
#pragma unroll
    for (int kc = 0; kc < 4; ++kc) {
#pragma unroll
      for (int kg = 0; kg < 4; ++kg) {
        const int row = kg * 16 + lo;
        bf16x8 kf = *(const bf16x8*)(Ks + row * 256 + ((((kc << 2) + hi) ^ (row & 7)) << 4));
        sc[kg] = MFMA16(qf[kc], kf, sc[kg]);
      }
    }
    // online softmax; D rows = hi*4 + reg
    float corr[4];
#pragma unroll
    for (int reg = 0; reg < 4; ++reg) {
      float v = fmaxf(fmaxf(sc[0][reg], sc[1][reg]), fmaxf(sc[2][reg], sc[3][reg])) * scale;
      v = fmaxf(v, __shfl_xor(v, 1));
      v = fmaxf(v, __shfl_xor(v, 2));
      v = fmaxf(v, __shfl_xor(v, 4));
      v = fmaxf(v, __shfl_xor(v, 8));
      const float mn = fmaxf(m[reg], v);
      corr[reg] = __expf(m[reg] - mn);
      m[reg] = mn;
      float rs = 0.f;
#pragma unroll
      for (int kg = 0; kg < 4; ++kg) {
        const float p = __expf(sc[kg][reg] * scale - mn);
        sc[kg][reg] = p;
        rs += p;
      }
      rs += __shfl_xor(rs, 1);
      rs += __shfl_xor(rs, 2);
      rs += __shfl_xor(rs, 4);
      rs += __shfl_xor(rs, 8);
      l[reg] = l[reg] * corr[reg] + rs;
    }
#pragma unroll
    for (int dg = 0; dg < 8; ++dg)
#pragma unroll
      for (int reg = 0; reg < 4; ++reg) oacc[dg][reg] *= corr[reg];

    // P -> LDS (bf16, swizzled rows of 128B); wave-private rows.
#pragma unroll
    for (int kg = 0; kg < 4; ++kg)
#pragma unroll
      for (int reg = 0; reg < 4; ++reg) {
        const int q = w * 16 + hi * 4 + reg;
        const int key = kg * 16 + lo;
        *(bf16*)(Ps + q * 128 + (((key >> 3) ^ (q & 7)) << 4) + ((key & 7) << 1)) =
            __float2bfloat16(sc[kg][reg]);
      }
    asm volatile("s_waitcnt lgkmcnt(0)" ::: "memory");

    bf16x8 pf[2];
#pragma unroll
    for (int kc = 0; kc < 2; ++kc) {
      const int prow = w * 16 + lo;
      pf[kc] = *(const bf16x8*)(Ps + prow * 128 + ((((kc << 2) + hi) ^ (prow & 7)) << 4));
    }
#pragma unroll
    for (int dg = 0; dg < 8; ++dg) {
#pragma unroll
      for (int kc = 0; kc < 2; ++kc) {
        const int vrow = dg * 16 + lo;
        bf16x8 vf = *(const bf16x8*)(Vs + vrow * 128 + ((((kc << 2) + hi) ^ (vrow & 7)) << 4));
        oacc[dg] = MFMA16(pf[kc], vf, oacc[dg]);
      }
    }
    __syncthreads();
  }

#pragma unroll
  for (int reg = 0; reg < 4; ++reg) l[reg] = 1.0f / l[reg];
  bf16* op = out + (tok0 + q0 + w * 16 + hi * 4) * 2048 + h * 128 + lo;
#pragma unroll
  for (int dg = 0; dg < 8; ++dg)
#pragma unroll
    for (int reg = 0; reg < 4; ++reg)
      op[(size_t)reg * 2048 + dg * 16] = __float2bfloat16(oacc[dg][reg] * l[reg]);
}

// ------------------------------------------------------------------ launch ----
extern "C" void kernel_launch(void* const* d_in, const int* in_sizes, int n_in,
                              void* d_out, int out_size, void* d_ws, size_t ws_size,
                              hipStream_t stream) {
  (void)in_sizes; (void)n_in; (void)out_size; (void)ws_size;
  const float* x  = (const float*)d_in[0];
  const float* s1 = (const float*)d_in[1];
  const float* Wq = (const float*)d_in[2];
  const float* bq = (const float*)d_in[3];
  const float* Wk = (const float*)d_in[4];
  const float* bk = (const float*)d_in[5];
  const float* Wv = (const float*)d_in[6];
  const float* bv = (const float*)d_in[7];
  const float* Wo = (const float*)d_in[8];
  const float* bo = (const float*)d_in[9];
  const float* W1 = (const float*)d_in[10];
  const float* b1 = (const float*)d_in[11];
  const float* W2 = (const float*)d_in[12];
  const float* b2 = (const float*)d_in[13];
  float* outp = (float*)d_out;

  char* ws = (char*)d_ws;
  bf16*  xn    = (bf16*)(ws + 0);            // 16 MB  [4096][2048]
  bf16*  wqkvT = (bf16*)(ws + 16777216);     // 12 MB  [3072][2048]
  float* bqkv  = (float*)(ws + 29360128);    // 16 KB
  bf16*  woT   = (bf16*)(ws + 29376512);     // 8 MB
  bf16*  w1T   = (bf16*)(ws + 37765120);     // 8 MB
  bf16*  w2T   = (bf16*)(ws + 46153728);     // 8 MB
  bf16*  qkvb  = (bf16*)(ws + 54542336);     // 24 MB  [4096][3072]
  bf16*  vtb   = (bf16*)(ws + 79708160);     // 4 MB   [16][128][1024]
  bf16*  attnb = (bf16*)(ws + 83902464);     // 16 MB  [4096][2048]
  bf16*  gbuf  = (bf16*)(ws + 54542336);     // aliases qkvb (dead after attn)
  float* x1    = outp;                       // residual mid lives in d_out

  const dim3 b32x8(32, 8);
  rmsnorm_cast_k<<<dim3(4096), dim3(256), 0, stream>>>(x, s1, xn);
  concat_bias_k<<<dim3(12), dim3(256), 0, stream>>>(bq, bk, bv, bqkv);
  transpose_cast_k<<<dim3(64, 64), b32x8, 0, stream>>>(Wq, wqkvT, 2048, 0);
  transpose_cast_k<<<dim3(16, 64), b32x8, 0, stream>>>(Wk, wqkvT, 512, 2048);
  transpose_cast_k<<<dim3(16, 64), b32x8, 0, stream>>>(Wv, wqkvT, 512, 2560);
  transpose_cast_k<<<dim3(64, 64), b32x8, 0, stream>>>(Wo, woT, 2048, 0);
  transpose_cast_k<<<dim3(64, 64), b32x8, 0, stream>>>(W1, w1T, 2048, 0);
  transpose_cast_k<<<dim3(64, 64), b32x8, 0, stream>>>(W2, w2T, 2048, 0);
  // QKV projection: [4096,2048] x [2048,3072]
  gemm_bt<0><<<dim3(32, 24), dim3(256), 0, stream>>>(xn, wqkvT, bqkv, (const float*)nullptr,
                                                     (void*)qkvb, 2048, 3072);
  transpose_v_k<<<dim3(32, 4, 16), b32x8, 0, stream>>>(qkvb, vtb);
  attn_fwd<<<dim3(16, 64), dim3(256), 0, stream>>>(qkvb, vtb, attnb);
  // x1 = x + attn @ Wo + bo   (written to d_out)
  gemm_bt<1><<<dim3(32, 16), dim3(256), 0, stream>>>(attnb, woT, bo, x, (void*)x1, 2048, 2048);
  // g = silu-sq(xn @ W1 + b1)
  gemm_bt<2><<<dim3(32, 16), dim3(256), 0, stream>>>(xn, w1T, b1, (const float*)nullptr,
                                                     (void*)gbuf, 2048, 2048);
  // out = x1 + g @ W2 + b2
  gemm_bt<1><<<dim3(32, 16), dim3(256), 0, stream>>>(gbuf, w2T, b2, x1, (void*)outp, 2048, 2048);
}

// Round 2
// 306.481 us; speedup vs baseline: 1.0899x; 1.0899x over previous
//
#include <hip/hip_runtime.h>
#include <hip/hip_bf16.h>
#include <cstdint>

using bf16 = __hip_bfloat16;
typedef __attribute__((ext_vector_type(8))) __bf16 bf16x8;
typedef __attribute__((ext_vector_type(4))) float f32x4;

#define MFMA16(a, b, c) __builtin_amdgcn_mfma_f32_16x16x32_bf16((a), (b), (c), 0, 0, 0)

#if __has_builtin(__builtin_amdgcn_exp2f)
__device__ __forceinline__ float fexp2(float x) { return __builtin_amdgcn_exp2f(x); }
#else
__device__ __forceinline__ float fexp2(float x) { return exp2f(x); }
#endif

// Async global->LDS 16B copy. LDS dest must be wave-uniform base + lane*16.
__device__ __forceinline__ void async16(void* lds_ptr, const void* gptr) {
  auto g = reinterpret_cast<__attribute__((address_space(1))) unsigned int*>(
      reinterpret_cast<uintptr_t>(gptr));
  auto l = reinterpret_cast<__attribute__((address_space(3))) unsigned int*>(
      static_cast<unsigned int>(reinterpret_cast<uintptr_t>(lds_ptr)));
  __builtin_amdgcn_global_load_lds(g, l, 16, 0, 0);
}

// ---------------------------------------------------------------- RMSNorm ----
__global__ __launch_bounds__(256) void rmsnorm_cast_k(
    const float* __restrict__ x, const float* __restrict__ sc, bf16* __restrict__ xn) {
  const int row = blockIdx.x, tid = threadIdx.x;
  const float4* xr = (const float4*)(x + (size_t)row * 2048);
  float4 a = xr[tid * 2], b = xr[tid * 2 + 1];
  float ss = a.x * a.x + a.y * a.y + a.z * a.z + a.w * a.w +
             b.x * b.x + b.y * b.y + b.z * b.z + b.w * b.w;
#pragma unroll
  for (int d = 1; d < 64; d <<= 1) ss += __shfl_xor(ss, d);
  __shared__ float sm[4];
  if ((tid & 63) == 0) sm[tid >> 6] = ss;
  __syncthreads();
  const float rinv = rsqrtf((sm[0] + sm[1] + sm[2] + sm[3]) * (1.0f / 2048.0f) + 1e-6f);
  const float4* sp = (const float4*)sc;
  float4 s0 = sp[tid * 2], s1 = sp[tid * 2 + 1];
  union { bf16 h[8]; bf16x8 v; } o;
  o.h[0] = __float2bfloat16(a.x * rinv * s0.x);
  o.h[1] = __float2bfloat16(a.y * rinv * s0.y);
  o.h[2] = __float2bfloat16(a.z * rinv * s0.z);
  o.h[3] = __float2bfloat16(a.w * rinv * s0.w);
  o.h[4] = __float2bfloat16(b.x * rinv * s1.x);
  o.h[5] = __float2bfloat16(b.y * rinv * s1.y);
  o.h[6] = __float2bfloat16(b.z * rinv * s1.z);
  o.h[7] = __float2bfloat16(b.w * rinv * s1.w);
  *(bf16x8*)(xn + (size_t)row * 2048 + tid * 8) = o.v;
}

// ------------------------------------------------- weight transpose + cast ----
__global__ void transpose_cast_k(const float* __restrict__ W, bf16* __restrict__ Wt,
                                 int N, int row_off) {
  __shared__ float t[32][33];
  const int n0 = blockIdx.x * 32, k0 = blockIdx.y * 32;
  const int tx = threadIdx.x, ty = threadIdx.y;
#pragma unroll
  for (int i = 0; i < 4; ++i)
    t[ty + 8 * i][tx] = W[(size_t)(k0 + ty + 8 * i) * N + n0 + tx];
  __syncthreads();
#pragma unroll
  for (int i = 0; i < 4; ++i)
    Wt[(size_t)(row_off + n0 + ty + 8 * i) * 2048 + k0 + tx] =
        __float2bfloat16(t[tx][ty + 8 * i]);
}

// V slice of QKV [4096][3072] (cols 2560..3071) -> Vt bf16 [16][128][1024]
__global__ void transpose_v_k(const bf16* __restrict__ qkv, bf16* __restrict__ vtb) {
  __shared__ bf16 t[32][33];
  const int bh = blockIdx.z, b = bh >> 2, g = bh & 3;
  const int s0 = blockIdx.x * 32, d0 = blockIdx.y * 32;
  const int tx = threadIdx.x, ty = threadIdx.y;
#pragma unroll
  for (int i = 0; i < 4; ++i)
    t[ty + 8 * i][tx] =
        qkv[(size_t)(b * 1024 + s0 + ty + 8 * i) * 3072 + 2560 + g * 128 + d0 + tx];
  __syncthreads();
#pragma unroll
  for (int i = 0; i < 4; ++i)
    vtb[((size_t)bh * 128 + d0 + ty + 8 * i) * 1024 + s0 + tx] = t[tx][ty + 8 * i];
}

__global__ void concat_bias_k(const float* __restrict__ bq, const float* __restrict__ bk,
                              const float* __restrict__ bv, float* __restrict__ o) {
  const int i = blockIdx.x * 256 + threadIdx.x;
  if (i < 2048) o[i] = bq[i];
  else if (i < 2560) o[i] = bk[i - 2048];
  else o[i] = bv[i - 2560];
}

// -------------------------------------------------------------------- GEMM ----
// C[M][N] = A[M][K] @ Bt[N][K]^T, bf16 in, f32 acc. 128x128 tile, BK=32, 4 waves.
template <int EPI>
__global__ __launch_bounds__(256, 3) void gemm_bt(
    const bf16* __restrict__ A, const bf16* __restrict__ Bt,
    const float* __restrict__ bias, const float* __restrict__ res,
    void* __restrict__ outp, int K, int ldout) {
  __shared__ __align__(16) unsigned char lds[16384];
  unsigned char* As = lds;
  unsigned char* Bs = lds + 8192;
  const int tid = threadIdx.x;
  const int lane = tid & 63, w = tid >> 6;
  const int wr = w >> 1, wc = w & 1;
  const int hi = lane >> 4, lo = lane & 15;
  const int brow = blockIdx.x * 128, bcol = blockIdx.y * 128;

  const int o0 = tid * 16, o1 = o0 + 4096;
  const int r0 = o0 >> 6, c0 = ((o0 >> 4) & 3) ^ ((r0 >> 1) & 3);
  const int r1 = o1 >> 6, c1 = ((o1 >> 4) & 3) ^ ((r1 >> 1) & 3);
  const bf16* gA0 = A + (size_t)(brow + r0) * K + c0 * 8;
  const bf16* gA1 = A + (size_t)(brow + r1) * K + c1 * 8;
  const bf16* gB0 = Bt + (size_t)(bcol + r0) * K + c0 * 8;
  const bf16* gB1 = Bt + (size_t)(bcol + r1) * K + c1 * 8;

  const int rowA = wr * 64 + lo;
  const int rowB = wc * 64 + lo;
  const int swzA = (hi ^ ((rowA >> 1) & 3)) << 4;
  const int swzB = (hi ^ ((rowB >> 1) & 3)) << 4;

  f32x4 acc[4][4] = {};

  for (int k0 = 0; k0 < K; k0 += 32) {
    async16(As + o0, gA0 + k0);
    async16(As + o1, gA1 + k0);
    async16(Bs + o0, gB0 + k0);
    async16(Bs + o1, gB1 + k0);
    __syncthreads();
    bf16x8 af[4], bfr[4];
#pragma unroll
    for (int i = 0; i < 4; ++i)
      af[i] = *(const bf16x8*)(As + (rowA + i * 16) * 64 + swzA);
#pragma unroll
    for (int j = 0; j < 4; ++j)
      bfr[j] = *(const bf16x8*)(Bs + (rowB + j * 16) * 64 + swzB);
#pragma unroll
    for (int i = 0; i < 4; ++i)
#pragma unroll
      for (int j = 0; j < 4; ++j)
        acc[i][j] = MFMA16(af[i], bfr[j], acc[i][j]);
    __syncthreads();
  }

#pragma unroll
  for (int j = 0; j < 4; ++j) {
    const int col = bcol + wc * 64 + j * 16 + lo;
    const float bs = bias[col];
#pragma unroll
    for (int i = 0; i < 4; ++i) {
      const int row = brow + wr * 64 + i * 16 + hi * 4;
#pragma unroll
      for (int r = 0; r < 4; ++r) {
        float v = acc[i][j][r] + bs;
        if (EPI == 1) v += res[(size_t)(row + r) * ldout + col];
        if (EPI == 2) {
          const float sg = 1.0f / (1.0f + __expf(-v));
          v = v * sg * v;
        }
        if (EPI == 1)
          ((float*)outp)[(size_t)(row + r) * ldout + col] = v;
        else
          ((bf16*)outp)[(size_t)(row + r) * ldout + col] = __float2bfloat16(v);
      }
    }
  }
}

// --------------------------------------------------------------- attention ----
// grid (16 q-tiles, 64 b*h), 4 waves; wave w owns q rows [w*16, w*16+16).
// Swapped QK^T: sc = mfma(K,Q) -> lane holds S[16 keys][q=w*16+lo].
// K tile [64][256B] swz chunk16^(row&15); Vt tile [128][128B] swz ^(row&7);
// P per-wave [16][128B] swz ^(q&7).
__global__ __launch_bounds__(256, 4) void attn_fwd(
    const bf16* __restrict__ qkv, const bf16* __restrict__ vtb, bf16* __restrict__ out) {
  __shared__ __align__(16) unsigned char lds[40960];
  unsigned char* Ks = lds;
  unsigned char* Vs = lds + 16384;
  unsigned char* Ps = lds + 32768;
  const int tid = threadIdx.x, lane = tid & 63, w = tid >> 6;
  const int hi = lane >> 4, lo = lane & 15;
  const int qt = blockIdx.x, bh = blockIdx.y;
  const int b = bh >> 4, h = bh & 15, g = h >> 2;
  const size_t tok0 = (size_t)b * 1024;
  const int q0 = qt * 64;

  // Q fragments (B-operand): lane holds Q[q=w*16+lo][d=kc*32+hi*8 ..+8]
  bf16x8 qf[4];
  {
    const bf16* qp = qkv + (tok0 + q0 + w * 16 + lo) * 3072 + h * 128 + hi * 8;
#pragma unroll
    for (int kc = 0; kc < 4; ++kc) qf[kc] = *(const bf16x8*)(qp + kc * 32);
  }

  float m2 = -1e30f, lsum = 0.f;  // per-lane softmax state for q = w*16+lo (log2 domain)
  f32x4 oacc[8] = {};
  const float c2 = 0.08838834764831845f * 1.44269504088896f;  // 1/sqrt(128) * log2(e)

  const int o = tid * 16;
  const bf16* kbase = qkv + tok0 * 3072 + 2048 + g * 128;
  const bf16* vbase = vtb + (size_t)(b * 4 + g) * 128 * 1024;
  unsigned char* Pw = Ps + w * 2048;

  for (int t = 0; t < 16; ++t) {
    const int kb = t * 64;
#pragma unroll
    for (int rd = 0; rd < 4; ++rd) {
      const int oo = o + rd * 4096;
      const int rK = oo >> 8, cK = ((oo >> 4) & 15) ^ (rK & 15);
      const int rV = oo >> 7, cV = ((oo >> 4) & 7) ^ (rV & 7);
      async16(Ks + oo, kbase + (size_t)(kb + rK) * 3072 + cK * 8);
      async16(Vs + oo, vbase + (size_t)rV * 1024 + kb + cV * 8);
    }
    __syncthreads();

    // S^T: sc[kg][reg] = S[key=kg*16+hi*4+reg][q=w*16+lo]
    f32x4 sc[4] = {};
#pragma unroll
    for (int kc = 0; kc < 4; ++kc) {
#pragma unroll
      for (int kg = 0; kg < 4; ++kg) {
        const int row = kg * 16 + lo;
        bf16x8 kf = *(const bf16x8*)(Ks + row * 256 + ((((kc << 2) + hi) ^ (row & 15)) << 4));
        sc[kg] = MFMA16(kf, qf[kc], sc[kg]);
      }
    }

    // online softmax for q = w*16+lo (scores spread over in-lane 16 + hi groups)
    float mx = sc[0][0];
#pragma unroll
    for (int kg = 0; kg < 4; ++kg)
#pragma unroll
      for (int r = 0; r < 4; ++r) mx = fmaxf(mx, sc[kg][r]);
    mx = fmaxf(mx, __shfl_xor(mx, 16));
    mx = fmaxf(mx, __shfl_xor(mx, 32));
    mx *= c2;
    const float mn = fmaxf(m2, mx);
    const float corr = fexp2(m2 - mn);
    m2 = mn;

    float rs = 0.f;
#pragma unroll
    for (int kg = 0; kg < 4; ++kg) {
      union { bf16 hh[4]; uint2 v; } pk;
#pragma unroll
      for (int r = 0; r < 4; ++r) {
        const float p = fexp2(sc[kg][r] * c2 - mn);
        rs += p;
        pk.hh[r] = __float2bfloat16(p);
      }
      // write keys kg*16+hi*4 .. +3 of row q=lo (chunk16 swizzle ^ (q&7))
      *(uint2*)(Pw + lo * 128 + ((((kg << 1) + (hi >> 1)) ^ (lo & 7)) << 4) +
                ((hi & 1) << 3)) = pk.v;
    }
    rs += __shfl_xor(rs, 16);
    rs += __shfl_xor(rs, 32);
    lsum = lsum * corr + rs;

    // rescale oacc rows (q = w*16+hi*4+r): broadcast corr from lane hi*4+r
    float corr_r[4];
#pragma unroll
    for (int r = 0; r < 4; ++r) corr_r[r] = __shfl(corr, hi * 4 + r);
#pragma unroll
    for (int dg = 0; dg < 8; ++dg)
#pragma unroll
      for (int r = 0; r < 4; ++r) oacc[dg][r] *= corr_r[r];

    asm volatile("s_waitcnt lgkmcnt(0)" ::: "memory");

    bf16x8 pf[2];
#pragma unroll
    for (int kc = 0; kc < 2; ++kc)
      pf[kc] = *(const bf16x8*)(Pw + lo * 128 + ((((kc << 2) + hi) ^ (lo & 7)) << 4));
#pragma unroll
    for (int dg = 0; dg < 8; ++dg) {
#pragma unroll
      for (int kc = 0; kc < 2; ++kc) {
        const int vrow = dg * 16 + lo;
        bf16x8 vf = *(const bf16x8*)(Vs + vrow * 128 + ((((kc << 2) + hi) ^ (vrow & 7)) << 4));
        oacc[dg] = MFMA16(pf[kc], vf, oacc[dg]);
      }
    }
    __syncthreads();
  }

  const float linv = 1.0f / lsum;
  float lr[4];
#pragma unroll
  for (int r = 0; r < 4; ++r) lr[r] = __shfl(linv, hi * 4 + r);
  bf16* op = out + (tok0 + q0 + w * 16 + hi * 4) * 2048 + h * 128 + lo;
#pragma unroll
  for (int dg = 0; dg < 8; ++dg)
#pragma unroll
    for (int r = 0; r < 4; ++r)
      op[(size_t)r * 2048 + dg * 16] = __float2bfloat16(oacc[dg][r] * lr[r]);
}

// ------------------------------------------------------------------ launch ----
extern "C" void kernel_launch(void* const* d_in, const int* in_sizes, int n_in,
                              void* d_out, int out_size, void* d_ws, size_t ws_size,
                              hipStream_t stream) {
  (void)in_sizes; (void)n_in; (void)out_size; (void)ws_size;
  const float* x  = (const float*)d_in[0];
  const float* s1 = (const float*)d_in[1];
  const float* Wq = (const float*)d_in[2];
  const float* bq = (const float*)d_in[3];
  const float* Wk = (const float*)d_in[4];
  const float* bk = (const float*)d_in[5];
  const float* Wv = (const float*)d_in[6];
  const float* bv = (const float*)d_in[7];
  const float* Wo = (const float*)d_in[8];
  const float* bo = (const float*)d_in[9];
  const float* W1 = (const float*)d_in[10];
  const float* b1 = (const float*)d_in[11];
  const float* W2 = (const float*)d_in[12];
  const float* b2 = (const float*)d_in[13];
  float* outp = (float*)d_out;

  char* ws = (char*)d_ws;
  bf16*  xn    = (bf16*)(ws + 0);            // 16 MB  [4096][2048]
  bf16*  wqkvT = (bf16*)(ws + 16777216);     // 12 MB  [3072][2048]
  float* bqkv  = (float*)(ws + 29360128);    // 16 KB
  bf16*  woT   = (bf16*)(ws + 29376512);     // 8 MB
  bf16*  w1T   = (bf16*)(ws + 37765120);     // 8 MB
  bf16*  w2T   = (bf16*)(ws + 46153728);     // 8 MB
  bf16*  qkvb  = (bf16*)(ws + 54542336);     // 24 MB  [4096][3072]
  bf16*  vtb   = (bf16*)(ws + 79708160);     // 4 MB   [16][128][1024]
  bf16*  attnb = (bf16*)(ws + 83902464);     // 16 MB  [4096][2048]
  bf16*  gbuf  = (bf16*)(ws + 54542336);     // aliases qkvb (dead after attn)
  float* x1    = outp;                       // residual mid lives in d_out

  const dim3 b32x8(32, 8);
  rmsnorm_cast_k<<<dim3(4096), dim3(256), 0, stream>>>(x, s1, xn);
  concat_bias_k<<<dim3(12), dim3(256), 0, stream>>>(bq, bk, bv, bqkv);
  transpose_cast_k<<<dim3(64, 64), b32x8, 0, stream>>>(Wq, wqkvT, 2048, 0);
  transpose_cast_k<<<dim3(16, 64), b32x8, 0, stream>>>(Wk, wqkvT, 512, 2048);
  transpose_cast_k<<<dim3(16, 64), b32x8, 0, stream>>>(Wv, wqkvT, 512, 2560);
  transpose_cast_k<<<dim3(64, 64), b32x8, 0, stream>>>(Wo, woT, 2048, 0);
  transpose_cast_k<<<dim3(64, 64), b32x8, 0, stream>>>(W1, w1T, 2048, 0);
  transpose_cast_k<<<dim3(64, 64), b32x8, 0, stream>>>(W2, w2T, 2048, 0);
  gemm_bt<0><<<dim3(32, 24), dim3(256), 0, stream>>>(xn, wqkvT, bqkv, (const float*)nullptr,
                                                     (void*)qkvb, 2048, 3072);
  transpose_v_k<<<dim3(32, 4, 16), b32x8, 0, stream>>>(qkvb, vtb);
  attn_fwd<<<dim3(16, 64), dim3(256), 0, stream>>>(qkvb, vtb, attnb);
  gemm_bt<1><<<dim3(32, 16), dim3(256), 0, stream>>>(attnb, woT, bo, x, (void*)x1, 2048, 2048);
  gemm_bt<2><<<dim3(32, 16), dim3(256), 0, stream>>>(xn, w1T, b1, (const float*)nullptr,
                                                     (void*)gbuf, 2048, 2048);
  gemm_bt<1><<<dim3(32, 16), dim3(256), 0, stream>>>(gbuf, w2T, b2, x1, (void*)outp, 2048, 2048);
}